// Round 7
// baseline (152.611 us; speedup 1.0000x reference)
//
#include <hip/hip_runtime.h>
#include <math.h>

#define B_    8
#define Q_    900
#define NCLS_ 11
#define NANC_ 100
#define H_    200
#define W_    200
#define C_    256
#define NEPAD_ 208          // 2*NANC_ padded to multiple of 8
#define CAP_  48            // features staged in LDS per block (48 KB)

// ---------------------------------------------------------------------------
// Kernel 1: scores + rank-based top-k + box->pixel coords (one block per batch)
// (unchanged — proven rounds 1-6)
// ---------------------------------------------------------------------------
__global__ __launch_bounds__(1024) void segdet_topk_kernel(
    const float* __restrict__ pred_boxes,   // [B,Q,4]
    const float* __restrict__ pred_logits,  // [B,Q,NCLS]
    const float* __restrict__ view,         // [B,5,5]
    int*  __restrict__ ws_idx,              // [B,NANC]  selected q index
    int4* __restrict__ ws_box)              // [B,NANC]  (x0,y0,x1,y1) clipped ints
{
    const int b = blockIdx.x;
    const int q = threadIdx.x;

    __shared__ float sc[Q_];

    if (q < Q_) {
        const float* l = pred_logits + (b * Q_ + q) * NCLS_;
        float v[NCLS_];
        float m = -INFINITY;
        #pragma unroll
        for (int i = 0; i < NCLS_; ++i) { v[i] = l[i]; m = fmaxf(m, v[i]); }
        float s = 0.0f, e10 = -INFINITY;
        #pragma unroll
        for (int i = 0; i < NCLS_; ++i) {
            float e = expf(v[i] - m);
            s += e;
            if (i < NCLS_ - 1) e10 = fmaxf(e10, e);   // exclude background (last)
        }
        sc[q] = e10 / s;
    }
    __syncthreads();

    if (q < Q_) {
        const float my = sc[q];
        int rank = 0;
        for (int j = 0; j < Q_; ++j) {
            float o = sc[j];
            rank += (o > my) || (o == my && j < q);   // top_k tie-break: lower idx first
        }
        if (rank < NANC_) {
            // box -> xyxy -> view transform -> trunc int -> clip, in double so the
            // int-truncation boundary matches the reference exactly.
            const float* bx = pred_boxes + (b * Q_ + q) * 4;
            double cx = (double)bx[0], cy = (double)bx[1];
            double w  = exp((double)bx[2]);
            double h  = exp((double)bx[3]);
            double p[5] = { cx - 0.5 * w, cy - 0.5 * h,
                            cx + 0.5 * w, cy + 0.5 * h, 1.0 };
            const float* v5 = view + b * 25;
            int ico[4];
            #pragma unroll
            for (int i = 0; i < 4; ++i) {
                double acc = 0.0;
                #pragma unroll
                for (int j = 0; j < 5; ++j) acc += (double)v5[i * 5 + j] * p[j];
                ico[i] = (int)acc;                    // trunc toward zero == astype(int32)
            }
            int x0 = min(max(ico[0], 0), W_);
            int y0 = min(max(ico[1], 0), H_);
            int x1 = min(max(ico[2], 0), W_);
            int y1 = min(max(ico[3], 0), H_);
            const int slot = b * NANC_ + rank;        // rank unique -> no atomics
            ws_idx[slot] = q;
            ws_box[slot] = make_int4(x0, y0, x1, y1);
        }
    }
}

// ---------------------------------------------------------------------------
// Kernel 2: BEV splat — LDS-staged features + lgkmcnt-decoupled event walk.
// One block per (b,h) row, 4 waves; wave wv owns pixels {wv, wv+4, ...}
// (balanced). Preamble stages the row's <=CAP_ active features into LDS;
// main loop processes entries in groups of 4: one uniform b128 entry read +
// four ds_read_b128 feature reads issued up front (lgkmcnt — NOT coupled to
// the store stream, unlike round 6's global loads on vmcnt), then 4 static
// {store-run, apply} steps. Overflow ranks >= CAP_ load from global (rare).
// Empty rows take a pure zero-fill fast path. Scratch-free.
// ---------------------------------------------------------------------------
__global__ __launch_bounds__(256) void segdet_bev_kernel(
    const float* __restrict__ box_feats,    // [B,Q,C]
    const int*   __restrict__ ws_idx,       // [B,NANC]
    const int4*  __restrict__ ws_box,       // [B,NANC]
    float* __restrict__ bev,                // [B,H,W,C]
    float* __restrict__ mask)               // [B,H,W] (0/1 floats)
{
    const int b   = blockIdx.x / H_;
    const int h   = blockIdx.x % H_;
    const int tid = threadIdx.x;
    const int ln  = tid & 63;
    const int wv  = tid >> 6;

    __shared__ __align__(16) float s_feat[CAP_ * C_];   // 48 KB staged features
    __shared__ int s_box[NANC_];            // x0 | x1<<8 | q<<16 (packed)
    __shared__ int s_nact;
    __shared__ int s_nopen[W_];             // # opens at pixel w
    __shared__ int s_ofs[W_];               // CSR offsets (exclusive scan)
    __shared__ __align__(16) int s_ent[NEPAD_];  // pix | rank<<8 | (close?1<<31:0)
    __shared__ int s_wsum[4];

    // ---- wave-0 ballot compaction of row-active anchors (deterministic order)
    if (tid < 64) {
        int na = 0;
        #pragma unroll
        for (int it = 0; it < 2; ++it) {
            int k = it * 64 + ln;
            bool act = false;
            int packed = 0;
            if (k < NANC_) {
                int4 bx = ws_box[b * NANC_ + k];
                int qi  = ws_idx[b * NANC_ + k];
                act = (bx.y <= h) && (h < bx.w) && (bx.x < bx.z);
                packed = bx.x | (bx.z << 8) | (qi << 16);
            }
            unsigned long long ball = __ballot(act);
            int pos = na + (int)__popcll(ball & ((1ull << ln) - 1ull));
            if (act) s_box[pos] = packed;
            na += (int)__popcll(ball);
        }
        if (ln == 0) s_nact = na;
    }
    __syncthreads();

    const int nact = s_nact;
    float* obase = bev + (size_t)(b * H_ + h) * W_ * C_ + ln * 4;

    // ---- empty-row fast path: zero fill + zero mask, skip everything else
    if (nact == 0) {
        const float4 z = make_float4(0.f, 0.f, 0.f, 0.f);
        for (int w = wv; w < W_; w += 4)
            *(float4*)(obase + (size_t)w * C_) = z;
        if (tid < W_) mask[(size_t)(b * H_ + h) * W_ + tid] = 0.0f;
        return;
    }

    // ---- per-pixel open/close counts + coverage (mask); sentinel-init s_ent
    int ntot = 0;
    if (tid < W_) {
        int nopen = 0, nclose = 0, cov = 0;
        for (int k = 0; k < nact; ++k) {
            int pk = s_box[k];                 // uniform LDS broadcast
            int x0 = pk & 0xFF, x1 = (pk >> 8) & 0xFF;
            nopen  += (x0 == tid);
            nclose += (x1 == tid);             // x1==200 auto-excluded (tid<200)
            cov    += (x0 <= tid) && (tid < x1);
        }
        s_nopen[tid] = nopen;
        ntot = nopen + nclose;
        mask[(size_t)(b * H_ + h) * W_ + tid] = (cov > 0) ? 1.0f : 0.0f;
    }
    if (tid < NEPAD_) s_ent[tid] = 0xFF;       // sentinel: pix=255, rank 0, sign +

    // ---- shuffle-based inclusive scan (6 steps) + cross-wave combine
    int incl = ntot;
    #pragma unroll
    for (int d = 1; d < 64; d <<= 1) {
        int u = __shfl_up(incl, d);
        incl = (ln >= d) ? incl + u : incl;
    }
    if (ln == 63) s_wsum[wv] = incl;
    __syncthreads();                            // also covers sentinel init
    int prev = 0;
    #pragma unroll
    for (int j = 0; j < 4; ++j) prev += (j < wv) ? s_wsum[j] : 0;
    const int ne = s_wsum[0] + s_wsum[1] + s_wsum[2] + s_wsum[3];
    if (tid < W_) s_ofs[tid] = prev + incl - ntot;   // exclusive scan
    __syncthreads();

    // ---- CSR entry scatter (rank-packed): one thread per active box, k-order
    if (tid < nact) {
        int pk = s_box[tid];
        int x0 = pk & 0xFF, x1 = (pk >> 8) & 0xFF;
        int ro = 0, rc = 0;
        for (int j = 0; j < tid; ++j) {
            int pj = s_box[j];
            ro += ((pj & 0xFF) == x0);
            rc += (((pj >> 8) & 0xFF) == x1);
        }
        s_ent[s_ofs[x0] + ro] = x0 | (tid << 8);                          // open
        if (x1 < W_)
            s_ent[s_ofs[x1] + s_nopen[x1] + rc] = x1 | (tid << 8) | (1 << 31); // close
    }

    // ---- stage features into LDS (wave-strided rows; independent 1KB copies)
    const float* fb = box_feats + (size_t)b * Q_ * C_ + ln * 4;
    const int nstage = (nact < CAP_) ? nact : CAP_;
    for (int k = wv; k < nstage; k += 4) {
        const int q = s_box[k] >> 16;           // uniform per wave
        const float4 f = *(const float4*)(fb + (size_t)q * C_);
        *(float4*)&s_feat[k * C_ + ln * 4] = f;
    }
    __syncthreads();

    // ---- main loop: 4-entry groups, LDS feature reads (lgkmcnt-decoupled)
    float4 acc = make_float4(0.f, 0.f, 0.f, 0.f);
    int cnt = 0;
    int w = wv;
    const int ngrp = (ne + 3) >> 2;             // uniform across all waves

#define LDF_(ENT, F)                                                          \
    {                                                                         \
        const int r_ = ((ENT) >> 8) & 0x7F;                                   \
        if (r_ < CAP_) F = *(const float4*)&s_feat[r_ * C_ + ln * 4];         \
        else F = *(const float4*)(fb + (size_t)(s_box[r_] >> 16) * C_);       \
    }
#define STEP_(ENT, F)                                                         \
    {                                                                         \
        const int pk_ = (ENT);                                                \
        const int px_ = pk_ & 0xFF;                                           \
        const int lim_ = (px_ < W_) ? px_ : W_;                               \
        for (; w < lim_; w += 4)                                              \
            *(float4*)(obase + (size_t)w * C_) = acc;                         \
        if (px_ < W_) {                                                       \
            if (pk_ < 0) { acc.x -= (F).x; acc.y -= (F).y;                    \
                           acc.z -= (F).z; acc.w -= (F).w; --cnt; }           \
            else         { acc.x += (F).x; acc.y += (F).y;                    \
                           acc.z += (F).z; acc.w += (F).w; ++cnt; }           \
            if (cnt == 0) acc = make_float4(0.f, 0.f, 0.f, 0.f);              \
        }                                                                     \
    }

    for (int g = 0; g < ngrp; ++g) {
        const int4 ew = *(const int4*)&s_ent[g * 4];    // uniform b128 broadcast
        float4 f0, f1, f2, f3;
        LDF_(ew.x, f0); LDF_(ew.y, f1); LDF_(ew.z, f2); LDF_(ew.w, f3);
        STEP_(ew.x, f0); STEP_(ew.y, f1); STEP_(ew.z, f2); STEP_(ew.w, f3);
    }
#undef LDF_
#undef STEP_
    for (; w < W_; w += 4)
        *(float4*)(obase + (size_t)w * C_) = acc;
}

// ---------------------------------------------------------------------------
extern "C" void kernel_launch(void* const* d_in, const int* in_sizes, int n_in,
                              void* d_out, int out_size, void* d_ws, size_t ws_size,
                              hipStream_t stream) {
    const float* pred_boxes  = (const float*)d_in[0];
    const float* pred_logits = (const float*)d_in[1];
    const float* box_feats   = (const float*)d_in[2];
    const float* view        = (const float*)d_in[3];

    float* bev  = (float*)d_out;
    float* mask = bev + (size_t)B_ * H_ * W_ * C_;

    int*  ws_idx = (int*)d_ws;                            // 800 ints = 3200 B
    int4* ws_box = (int4*)((char*)d_ws + 3200);           // 800 int4 (16B aligned)

    segdet_topk_kernel<<<B_, 1024, 0, stream>>>(pred_boxes, pred_logits, view,
                                                ws_idx, ws_box);
    segdet_bev_kernel<<<B_ * H_, 256, 0, stream>>>(box_feats, ws_idx, ws_box,
                                                   bev, mask);
}

// Round 8
// 114.219 us; speedup vs baseline: 1.3361x; 1.3361x over previous
//
#include <hip/hip_runtime.h>
#include <math.h>

#define B_    8
#define Q_    900
#define NCLS_ 11
#define NANC_ 100
#define H_    200
#define W_    200
#define C_    256
#define HHALF 100           // split pixel: waves 0,1 -> [0,100), waves 2,3 -> [100,200)

// ---------------------------------------------------------------------------
// Kernel 1: scores + rank-based top-k + box->pixel coords (one block per batch)
// (unchanged — proven rounds 1-7)
// ---------------------------------------------------------------------------
__global__ __launch_bounds__(1024) void segdet_topk_kernel(
    const float* __restrict__ pred_boxes,   // [B,Q,4]
    const float* __restrict__ pred_logits,  // [B,Q,NCLS]
    const float* __restrict__ view,         // [B,5,5]
    int*  __restrict__ ws_idx,              // [B,NANC]  selected q index
    int4* __restrict__ ws_box)              // [B,NANC]  (x0,y0,x1,y1) clipped ints
{
    const int b = blockIdx.x;
    const int q = threadIdx.x;

    __shared__ float sc[Q_];

    if (q < Q_) {
        const float* l = pred_logits + (b * Q_ + q) * NCLS_;
        float v[NCLS_];
        float m = -INFINITY;
        #pragma unroll
        for (int i = 0; i < NCLS_; ++i) { v[i] = l[i]; m = fmaxf(m, v[i]); }
        float s = 0.0f, e10 = -INFINITY;
        #pragma unroll
        for (int i = 0; i < NCLS_; ++i) {
            float e = expf(v[i] - m);
            s += e;
            if (i < NCLS_ - 1) e10 = fmaxf(e10, e);   // exclude background (last)
        }
        sc[q] = e10 / s;
    }
    __syncthreads();

    if (q < Q_) {
        const float my = sc[q];
        int rank = 0;
        for (int j = 0; j < Q_; ++j) {
            float o = sc[j];
            rank += (o > my) || (o == my && j < q);   // top_k tie-break: lower idx first
        }
        if (rank < NANC_) {
            // box -> xyxy -> view transform -> trunc int -> clip, in double so the
            // int-truncation boundary matches the reference exactly.
            const float* bx = pred_boxes + (b * Q_ + q) * 4;
            double cx = (double)bx[0], cy = (double)bx[1];
            double w  = exp((double)bx[2]);
            double h  = exp((double)bx[3]);
            double p[5] = { cx - 0.5 * w, cy - 0.5 * h,
                            cx + 0.5 * w, cy + 0.5 * h, 1.0 };
            const float* v5 = view + b * 25;
            int ico[4];
            #pragma unroll
            for (int i = 0; i < 4; ++i) {
                double acc = 0.0;
                #pragma unroll
                for (int j = 0; j < 5; ++j) acc += (double)v5[i * 5 + j] * p[j];
                ico[i] = (int)acc;                    // trunc toward zero == astype(int32)
            }
            int x0 = min(max(ico[0], 0), W_);
            int y0 = min(max(ico[1], 0), H_);
            int x1 = min(max(ico[2], 0), W_);
            int y1 = min(max(ico[3], 0), H_);
            const int slot = b * NANC_ + rank;        // rank unique -> no atomics
            ws_idx[slot] = q;
            ws_box[slot] = make_int4(x0, y0, x1, y1);
        }
    }
}

// ---------------------------------------------------------------------------
// Kernel 2: BEV splat = round-4 structure (proven 112us) with 3 deltas:
//  (a) half-split walk: waves 0,1 own pixels {wv,wv+2,..}<100; waves 2,3 own
//      [100,200). Each wave applies only its half's events -> serial event
//      chain and duplicate feature loads halved. Upper waves batch-init
//      coverage at pixel 100 (k-order, independent loads).
//  (b) center-out (LPT) block order: heavy central rows dispatch first.
//  (c) empty-row fast path (zero fill, skip scan/scatter).
// Everything else (preamble, CSR, on-demand loads, tiny LDS) is R4 verbatim.
// ---------------------------------------------------------------------------
__global__ __launch_bounds__(256) void segdet_bev_kernel(
    const float* __restrict__ box_feats,    // [B,Q,C]
    const int*   __restrict__ ws_idx,       // [B,NANC]
    const int4*  __restrict__ ws_box,       // [B,NANC]
    float* __restrict__ bev,                // [B,H,W,C]
    float* __restrict__ mask)               // [B,H,W] (0/1 floats)
{
    // center-out row order: hidx 0,1,2,3,... -> h 100,99,101,98,...
    const int hidx = blockIdx.x / B_;
    const int b    = blockIdx.x % B_;
    const int h    = (hidx & 1) ? (HHALF - 1 - (hidx >> 1)) : (HHALF + (hidx >> 1));

    const int tid = threadIdx.x;
    const int ln  = tid & 63;
    const int wv  = tid >> 6;

    __shared__ int s_box[NANC_];            // x0 | x1<<8 | q<<16 (packed)
    __shared__ int s_nact;
    __shared__ int s_nopen[W_];             // # opens at pixel w
    __shared__ int s_scan[256];             // scan workspace
    __shared__ int s_ofs[W_ + 1];           // CSR offsets (exclusive scan)
    __shared__ int s_evpos[W_];             // ascending event pixels
    __shared__ int s_ent[2 * NANC_];        // q | (close ? 1<<31 : 0)
    __shared__ int s_wtot[4];
    __shared__ int s_plow;                  // event pixels <= HHALF in wave-1 span
    __shared__ int s_nev;

    // ---- wave-0 ballot compaction of row-active anchors (deterministic order)
    if (tid < 64) {
        int na = 0;
        #pragma unroll
        for (int it = 0; it < 2; ++it) {
            int k = it * 64 + ln;
            bool act = false;
            int packed = 0;
            if (k < NANC_) {
                int4 bx = ws_box[b * NANC_ + k];
                int qi  = ws_idx[b * NANC_ + k];
                act = (bx.y <= h) && (h < bx.w) && (bx.x < bx.z);
                packed = bx.x | (bx.z << 8) | (qi << 16);
            }
            unsigned long long ball = __ballot(act);
            int pos = na + (int)__popcll(ball & ((1ull << ln) - 1ull));
            if (act) s_box[pos] = packed;
            na += (int)__popcll(ball);
        }
        if (ln == 0) s_nact = na;
    }
    __syncthreads();

    const int nact = s_nact;
    float* obase = bev + (size_t)(b * H_ + h) * W_ * C_ + ln * 4;
    float* mrow  = mask + (size_t)(b * H_ + h) * W_;

    // ---- empty-row fast path
    if (nact == 0) {
        const float4 z = make_float4(0.f, 0.f, 0.f, 0.f);
        for (int w = wv; w < W_; w += 4)
            *(float4*)(obase + (size_t)w * C_) = z;
        if (tid < W_) mrow[tid] = 0.0f;
        return;
    }

    // ---- per-pixel open/close counts + coverage (mask), in parallel
    int ntot = 0;
    if (tid < W_) {
        int nopen = 0, nclose = 0, cov = 0;
        for (int k = 0; k < nact; ++k) {
            int pk = s_box[k];                 // uniform LDS broadcast
            int x0 = pk & 0xFF, x1 = (pk >> 8) & 0xFF;
            nopen  += (x0 == tid);
            nclose += (x1 == tid);             // x1==200 auto-excluded (tid<200)
            cov    += (x0 <= tid) && (tid < x1);
        }
        s_nopen[tid] = nopen;
        ntot = nopen + nclose;
        mrow[tid] = (cov > 0) ? 1.0f : 0.0f;
    }
    s_scan[tid] = ntot;
    __syncthreads();

    // ---- Hillis-Steele inclusive scan over 256 entries (R4 verbatim)
    #pragma unroll
    for (int d = 1; d < 256; d <<= 1) {
        int v = s_scan[tid];
        int u = (tid >= d) ? s_scan[tid - d] : 0;
        __syncthreads();
        s_scan[tid] = v + u;
        __syncthreads();
    }
    if (tid < W_) s_ofs[tid] = s_scan[tid] - ntot;   // exclusive scan
    if (tid == 0) s_ofs[W_] = s_scan[255];           // total entries

    // ---- event-pixel compaction (ascending order) + lower-half event count
    bool flag = (tid < W_) && (ntot > 0);
    unsigned long long bal = __ballot(flag);
    if (ln == 0) s_wtot[wv] = (int)__popcll(bal);
    if (wv == 1 && ln == 0)                          // tids 64..100 -> lanes 0..36
        s_plow = (int)__popcll(bal & ((1ull << 37) - 1ull));
    __syncthreads();
    int off = 0;
    for (int i = 0; i < wv; ++i) off += s_wtot[i];
    if (flag) s_evpos[off + (int)__popcll(bal & ((1ull << ln) - 1ull))] = tid;
    if (tid == 0) s_nev = s_wtot[0] + s_wtot[1] + s_wtot[2] + s_wtot[3];

    // ---- CSR entry scatter: one thread per active box, stable k-order
    if (tid < nact) {
        int pk = s_box[tid];
        int x0 = pk & 0xFF, x1 = (pk >> 8) & 0xFF, q = pk >> 16;
        int ro = 0, rc = 0;
        for (int j = 0; j < tid; ++j) {
            int pj = s_box[j];
            ro += ((pj & 0xFF) == x0);
            rc += (((pj >> 8) & 0xFF) == x1);
        }
        s_ent[s_ofs[x0] + ro] = q;                                        // open
        if (x1 < W_) s_ent[s_ofs[x1] + s_nopen[x1] + rc] = q | (1 << 31); // close
    }
    __syncthreads();

    // ---- half-split walk: waves 0,1 -> [0,100) stride 2; waves 2,3 -> [100,200)
    const int nev = s_nev;
    const bool upper = (wv >= 2);
    const int  wbeg  = upper ? (HHALF + (wv - 2)) : wv;
    const int  wlim  = upper ? W_ : HHALF;
    const int  p_lo  = s_wtot[0] + s_plow;           // # event pixels <= HHALF

    const float* fbase = box_feats + (size_t)b * Q_ * C_ + ln * 4;

    float4 acc = make_float4(0.f, 0.f, 0.f, 0.f);
    int cnt = 0;
    if (upper) {
        // init: coverage state at pixel HHALF (k-order; independent loads)
        for (int k = 0; k < nact; ++k) {
            int pk = s_box[k];
            int x0 = pk & 0xFF, x1 = (pk >> 8) & 0xFF;
            if (x0 <= HHALF && HHALF < x1) {
                const float4 f = *(const float4*)(fbase + (size_t)(pk >> 16) * C_);
                acc.x += f.x; acc.y += f.y; acc.z += f.z; acc.w += f.w;
                ++cnt;
            }
        }
    }
    int p = upper ? p_lo : 0;
    int nextpix = (p < nev) ? s_evpos[p] : W_;
    for (int w = wbeg; w < wlim; w += 2) {
        while (w >= nextpix) {                        // apply events passed
            int e1 = s_ofs[nextpix + 1];
            for (int e = s_ofs[nextpix]; e < e1; ++e) {
                int ent = s_ent[e];                   // uniform broadcast
                int q = ent & 0xFFFF;
                const float4 f = *(const float4*)(fbase + (size_t)q * C_);
                if (ent < 0) { acc.x -= f.x; acc.y -= f.y; acc.z -= f.z; acc.w -= f.w; --cnt; }
                else         { acc.x += f.x; acc.y += f.y; acc.z += f.z; acc.w += f.w; ++cnt; }
            }
            ++p;
            nextpix = (p < nev) ? s_evpos[p] : W_;
        }
        if (cnt == 0) acc = make_float4(0.f, 0.f, 0.f, 0.f);  // exact zeros
        *(float4*)(obase + (size_t)w * C_) = acc;
    }
}

// ---------------------------------------------------------------------------
extern "C" void kernel_launch(void* const* d_in, const int* in_sizes, int n_in,
                              void* d_out, int out_size, void* d_ws, size_t ws_size,
                              hipStream_t stream) {
    const float* pred_boxes  = (const float*)d_in[0];
    const float* pred_logits = (const float*)d_in[1];
    const float* box_feats   = (const float*)d_in[2];
    const float* view        = (const float*)d_in[3];

    float* bev  = (float*)d_out;
    float* mask = bev + (size_t)B_ * H_ * W_ * C_;

    int*  ws_idx = (int*)d_ws;                            // 800 ints = 3200 B
    int4* ws_box = (int4*)((char*)d_ws + 3200);           // 800 int4 (16B aligned)

    segdet_topk_kernel<<<B_, 1024, 0, stream>>>(pred_boxes, pred_logits, view,
                                                ws_idx, ws_box);
    segdet_bev_kernel<<<B_ * H_, 256, 0, stream>>>(box_feats, ws_idx, ws_box,
                                                   bev, mask);
}

// Round 10
// 112.972 us; speedup vs baseline: 1.3509x; 1.0110x over previous
//
#include <hip/hip_runtime.h>
#include <math.h>

#define B_    8
#define Q_    900
#define NCLS_ 11
#define NANC_ 100
#define H_    200
#define W_    200
#define C_    256
#define HHALF 100           // split pixel: waves 0,1 -> [0,100), waves 2,3 -> [100,200)

typedef float f32x4_ __attribute__((ext_vector_type(4)));   // native vec for nt-store

// ---------------------------------------------------------------------------
// Kernel 1: scores + rank-based top-k + box->pixel coords (one block per batch)
// (unchanged — proven rounds 1-8)
// ---------------------------------------------------------------------------
__global__ __launch_bounds__(1024) void segdet_topk_kernel(
    const float* __restrict__ pred_boxes,   // [B,Q,4]
    const float* __restrict__ pred_logits,  // [B,Q,NCLS]
    const float* __restrict__ view,         // [B,5,5]
    int*  __restrict__ ws_idx,              // [B,NANC]  selected q index
    int4* __restrict__ ws_box)              // [B,NANC]  (x0,y0,x1,y1) clipped ints
{
    const int b = blockIdx.x;
    const int q = threadIdx.x;

    __shared__ float sc[Q_];

    if (q < Q_) {
        const float* l = pred_logits + (b * Q_ + q) * NCLS_;
        float v[NCLS_];
        float m = -INFINITY;
        #pragma unroll
        for (int i = 0; i < NCLS_; ++i) { v[i] = l[i]; m = fmaxf(m, v[i]); }
        float s = 0.0f, e10 = -INFINITY;
        #pragma unroll
        for (int i = 0; i < NCLS_; ++i) {
            float e = expf(v[i] - m);
            s += e;
            if (i < NCLS_ - 1) e10 = fmaxf(e10, e);   // exclude background (last)
        }
        sc[q] = e10 / s;
    }
    __syncthreads();

    if (q < Q_) {
        const float my = sc[q];
        int rank = 0;
        for (int j = 0; j < Q_; ++j) {
            float o = sc[j];
            rank += (o > my) || (o == my && j < q);   // top_k tie-break: lower idx first
        }
        if (rank < NANC_) {
            // box -> xyxy -> view transform -> trunc int -> clip, in double so the
            // int-truncation boundary matches the reference exactly.
            const float* bx = pred_boxes + (b * Q_ + q) * 4;
            double cx = (double)bx[0], cy = (double)bx[1];
            double w  = exp((double)bx[2]);
            double h  = exp((double)bx[3]);
            double p[5] = { cx - 0.5 * w, cy - 0.5 * h,
                            cx + 0.5 * w, cy + 0.5 * h, 1.0 };
            const float* v5 = view + b * 25;
            int ico[4];
            #pragma unroll
            for (int i = 0; i < 4; ++i) {
                double acc = 0.0;
                #pragma unroll
                for (int j = 0; j < 5; ++j) acc += (double)v5[i * 5 + j] * p[j];
                ico[i] = (int)acc;                    // trunc toward zero == astype(int32)
            }
            int x0 = min(max(ico[0], 0), W_);
            int y0 = min(max(ico[1], 0), H_);
            int x1 = min(max(ico[2], 0), W_);
            int y1 = min(max(ico[3], 0), H_);
            const int slot = b * NANC_ + rank;        // rank unique -> no atomics
            ws_idx[slot] = q;
            ws_box[slot] = make_int4(x0, y0, x1, y1);
        }
    }
}

__device__ __forceinline__ void nt_store4(float* p, float4 v) {
    f32x4_ nv = { v.x, v.y, v.z, v.w };
    __builtin_nontemporal_store(nv, (f32x4_*)p);     // keep write stream out of L2
}

// ---------------------------------------------------------------------------
// Kernel 2: BEV splat = round-8 structure (114us) with 2 surgical deltas:
//  (a) shuffle-based scan replaces 16-barrier Hillis-Steele: 21 -> 4 barriers
//  (b) non-temporal stores for bev+mask so the 327MB write stream stops
//      evicting box_feats from L2 (FETCH_SIZE showed 5.6x refetch)
// Everything else (half-split walk, center-out order, on-demand event loads,
// empty fast path) is R8 verbatim. Scratch-free.
// ---------------------------------------------------------------------------
__global__ __launch_bounds__(256) void segdet_bev_kernel(
    const float* __restrict__ box_feats,    // [B,Q,C]
    const int*   __restrict__ ws_idx,       // [B,NANC]
    const int4*  __restrict__ ws_box,       // [B,NANC]
    float* __restrict__ bev,                // [B,H,W,C]
    float* __restrict__ mask)               // [B,H,W] (0/1 floats)
{
    // center-out row order: hidx 0,1,2,3,... -> h 100,99,101,98,...
    const int hidx = blockIdx.x / B_;
    const int b    = blockIdx.x % B_;
    const int h    = (hidx & 1) ? (HHALF - 1 - (hidx >> 1)) : (HHALF + (hidx >> 1));

    const int tid = threadIdx.x;
    const int ln  = tid & 63;
    const int wv  = tid >> 6;

    __shared__ int s_box[NANC_];            // x0 | x1<<8 | q<<16 (packed)
    __shared__ int s_nact;
    __shared__ int s_nopen[W_];             // # opens at pixel w
    __shared__ int s_ofs[W_ + 1];           // CSR offsets (exclusive scan)
    __shared__ int s_evpos[W_];             // ascending event pixels
    __shared__ int s_ent[2 * NANC_];        // q | (close ? 1<<31 : 0)
    __shared__ int s_wsum[4];               // per-wave ENTRY totals (scan)
    __shared__ int s_wtot[4];               // per-wave event-PIXEL counts
    __shared__ int s_plow;                  // event pixels 64..100 (wave-1 low lanes)

    // ---- wave-0 ballot compaction of row-active anchors (deterministic order)
    if (tid < 64) {
        int na = 0;
        #pragma unroll
        for (int it = 0; it < 2; ++it) {
            int k = it * 64 + ln;
            bool act = false;
            int packed = 0;
            if (k < NANC_) {
                int4 bx = ws_box[b * NANC_ + k];
                int qi  = ws_idx[b * NANC_ + k];
                act = (bx.y <= h) && (h < bx.w) && (bx.x < bx.z);
                packed = bx.x | (bx.z << 8) | (qi << 16);
            }
            unsigned long long ball = __ballot(act);
            int pos = na + (int)__popcll(ball & ((1ull << ln) - 1ull));
            if (act) s_box[pos] = packed;
            na += (int)__popcll(ball);
        }
        if (ln == 0) s_nact = na;
    }
    __syncthreads();                                   // barrier #1

    const int nact = s_nact;
    float* obase = bev + (size_t)(b * H_ + h) * W_ * C_ + ln * 4;
    float* mrow  = mask + (size_t)(b * H_ + h) * W_;

    // ---- empty-row fast path
    if (nact == 0) {
        const float4 z = make_float4(0.f, 0.f, 0.f, 0.f);
        for (int w = wv; w < W_; w += 4)
            nt_store4(obase + (size_t)w * C_, z);
        if (tid < W_) __builtin_nontemporal_store(0.0f, &mrow[tid]);
        return;
    }

    // ---- per-pixel open/close counts + coverage (mask), in parallel
    int ntot = 0;
    if (tid < W_) {
        int nopen = 0, nclose = 0, cov = 0;
        for (int k = 0; k < nact; ++k) {
            int pk = s_box[k];                 // uniform LDS broadcast
            int x0 = pk & 0xFF, x1 = (pk >> 8) & 0xFF;
            nopen  += (x0 == tid);
            nclose += (x1 == tid);             // x1==200 auto-excluded (tid<200)
            cov    += (x0 <= tid) && (tid < x1);
        }
        s_nopen[tid] = nopen;
        ntot = nopen + nclose;
        __builtin_nontemporal_store((cov > 0) ? 1.0f : 0.0f, &mrow[tid]);
    }

    // ---- shuffle-based inclusive scan of entry counts (6 steps, in-wave)
    int incl = ntot;
    #pragma unroll
    for (int d = 1; d < 64; d <<= 1) {
        int u = __shfl_up(incl, d);
        incl = (ln >= d) ? incl + u : incl;
    }
    if (ln == 63) s_wsum[wv] = incl;

    // ---- event-pixel ballot (flag = any entry at this pixel)
    const bool flag = (tid < W_) && (ntot > 0);
    const unsigned long long bal = __ballot(flag);
    if (ln == 0) s_wtot[wv] = (int)__popcll(bal);
    if (wv == 1 && ln == 0)                            // lanes 0..36 = pixels 64..100
        s_plow = (int)__popcll(bal & ((1ull << 37) - 1ull));
    __syncthreads();                                   // barrier #2

    int prev = 0;
    #pragma unroll
    for (int j = 0; j < 4; ++j) prev += (j < wv) ? s_wsum[j] : 0;
    const int ne = s_wsum[0] + s_wsum[1] + s_wsum[2] + s_wsum[3];
    if (tid < W_) s_ofs[tid] = prev + incl - ntot;     // exclusive entry scan
    if (tid == 0) s_ofs[W_] = ne;

    const int nev = s_wtot[0] + s_wtot[1] + s_wtot[2] + s_wtot[3];
    int eoff = 0;
    #pragma unroll
    for (int j = 0; j < 4; ++j) eoff += (j < wv) ? s_wtot[j] : 0;
    if (flag) s_evpos[eoff + (int)__popcll(bal & ((1ull << ln) - 1ull))] = tid;
    __syncthreads();                                   // barrier #3 (s_ofs ready)

    // ---- CSR entry scatter: one thread per active box, stable k-order
    if (tid < nact) {
        int pk = s_box[tid];
        int x0 = pk & 0xFF, x1 = (pk >> 8) & 0xFF, q = pk >> 16;
        int ro = 0, rc = 0;
        for (int j = 0; j < tid; ++j) {
            int pj = s_box[j];
            ro += ((pj & 0xFF) == x0);
            rc += (((pj >> 8) & 0xFF) == x1);
        }
        s_ent[s_ofs[x0] + ro] = q;                                        // open
        if (x1 < W_) s_ent[s_ofs[x1] + s_nopen[x1] + rc] = q | (1 << 31); // close
    }
    __syncthreads();                                   // barrier #4

    // ---- half-split walk: waves 0,1 -> [0,100) stride 2; waves 2,3 -> [100,200)
    const bool upper = (wv >= 2);
    const int  wbeg  = upper ? (HHALF + (wv - 2)) : wv;
    const int  wlim  = upper ? W_ : HHALF;
    const int  p_lo  = s_wtot[0] + s_plow;             // # event pixels <= HHALF

    const float* fbase = box_feats + (size_t)b * Q_ * C_ + ln * 4;

    float4 acc = make_float4(0.f, 0.f, 0.f, 0.f);
    int cnt = 0;
    if (upper) {
        // init: coverage state at pixel HHALF (k-order; independent loads)
        for (int k = 0; k < nact; ++k) {
            int pk = s_box[k];
            int x0 = pk & 0xFF, x1 = (pk >> 8) & 0xFF;
            if (x0 <= HHALF && HHALF < x1) {
                const float4 f = *(const float4*)(fbase + (size_t)(pk >> 16) * C_);
                acc.x += f.x; acc.y += f.y; acc.z += f.z; acc.w += f.w;
                ++cnt;
            }
        }
    }
    int p = upper ? p_lo : 0;
    int nextpix = (p < nev) ? s_evpos[p] : W_;
    for (int w = wbeg; w < wlim; w += 2) {
        while (w >= nextpix) {                         // apply events passed
            int e1 = s_ofs[nextpix + 1];
            for (int e = s_ofs[nextpix]; e < e1; ++e) {
                int ent = s_ent[e];                    // uniform broadcast
                int q = ent & 0xFFFF;
                const float4 f = *(const float4*)(fbase + (size_t)q * C_);
                if (ent < 0) { acc.x -= f.x; acc.y -= f.y; acc.z -= f.z; acc.w -= f.w; --cnt; }
                else         { acc.x += f.x; acc.y += f.y; acc.z += f.z; acc.w += f.w; ++cnt; }
            }
            ++p;
            nextpix = (p < nev) ? s_evpos[p] : W_;
        }
        if (cnt == 0) acc = make_float4(0.f, 0.f, 0.f, 0.f);  // exact zeros
        nt_store4(obase + (size_t)w * C_, acc);
    }
}

// ---------------------------------------------------------------------------
extern "C" void kernel_launch(void* const* d_in, const int* in_sizes, int n_in,
                              void* d_out, int out_size, void* d_ws, size_t ws_size,
                              hipStream_t stream) {
    const float* pred_boxes  = (const float*)d_in[0];
    const float* pred_logits = (const float*)d_in[1];
    const float* box_feats   = (const float*)d_in[2];
    const float* view        = (const float*)d_in[3];

    float* bev  = (float*)d_out;
    float* mask = bev + (size_t)B_ * H_ * W_ * C_;

    int*  ws_idx = (int*)d_ws;                            // 800 ints = 3200 B
    int4* ws_box = (int4*)((char*)d_ws + 3200);           // 800 int4 (16B aligned)

    segdet_topk_kernel<<<B_, 1024, 0, stream>>>(pred_boxes, pred_logits, view,
                                                ws_idx, ws_box);
    segdet_bev_kernel<<<B_ * H_, 256, 0, stream>>>(box_feats, ws_idx, ws_box,
                                                   bev, mask);
}